// Round 8
// baseline (78.206 us; speedup 1.0000x reference)
//
#include <hip/hip_runtime.h>

// Quantum circuit sim: 12 wires, DIM=4096, 3 layers, batch=512, fp32.
// R8: TLP push that respects the grid limit. Grid is fixed at 512 blocks
// (1 state/block) = 2 blocks/CU; the ONLY way to more waves/SIMD is bigger
// blocks. 512 threads -> 16 waves/CU = 4 waves/SIMD (R7 had 2).
//  - PER=8 amps/thread, 4 stages x 3 in-register wires per layer.
//  - R6 inline-asm v_pk complex core (8 VOP3P per gate-pair).
//  - Double-buffered LDS (74.9 KB/block, fits 2 blocks/CU exactly):
//    stage writes alternate b0,b1,b0,b1 -> no anti-dep barriers; 12 barriers
//    total, each covered by 4 waves/SIMD of latency hiding.
//  - Layout f(i) = 18*(i>>4)+(i&15): per-stage addressing = base VGPR +
//    immediate offsets; bank-conflict structural-minimum in every stage;
//    P3 keeps 16-B-aligned b128 pairs.
//  - CNOT chain folded to Gray map perm(i)=i^(i>>1): gather addresses
//    precomputed once per thread; final perm folded into measurement
//    weights via inverse-Gray.

namespace {

typedef float v2f __attribute__((ext_vector_type(2)));

constexpr int N_WIRES  = 12;
constexpr int DIM      = 1 << N_WIRES;        // 4096
constexpr int THREADS  = 512;
constexpr int PER      = 8;                   // amps per thread
constexpr int NGATES   = 36;
constexpr int PADC     = 4606;                // max f(i) = 18*255+15 = 4605

// ---- Packed complex helpers. v2f = (re, im) in a VGPR pair.
// d = u * p:
//   inst1: d.lo = p.re*u.re          d.hi = p.im*u.re
//   inst2: d.lo += p.im*(-u.im)      d.hi += p.re*u.im
__device__ __forceinline__ v2f cmul(v2f u, v2f p) {
    v2f d;
    asm("v_pk_mul_f32 %0, %1, %2 op_sel_hi:[1,0]"
        : "=v"(d) : "v"(p), "v"(u));
    asm("v_pk_fma_f32 %0, %1, %2, %0 op_sel:[1,1,0] op_sel_hi:[0,1,1] neg_lo:[0,1,0]"
        : "+v"(d) : "v"(p), "v"(u));
    return d;
}
// d += u * p
__device__ __forceinline__ void cfma(v2f& d, v2f u, v2f p) {
    asm("v_pk_fma_f32 %0, %1, %2, %0 op_sel_hi:[1,0,1]"
        : "+v"(d) : "v"(p), "v"(u));
    asm("v_pk_fma_f32 %0, %1, %2, %0 op_sel:[1,1,0] op_sel_hi:[0,1,1] neg_lo:[0,1,0]"
        : "+v"(d) : "v"(p), "v"(u));
}

// 3 in-register gates; gate gg pairs k-bit (2-gg). Um[g] = {u00,u01,u10,u11}.
__device__ __forceinline__ void apply3(v2f amp[PER], const v2f (*Um)[4], int gbase)
{
    #pragma unroll
    for (int gg = 0; gg < 3; ++gg) {
        const v2f u00 = Um[gbase + gg][0];
        const v2f u01 = Um[gbase + gg][1];
        const v2f u10 = Um[gbase + gg][2];
        const v2f u11 = Um[gbase + gg][3];
        const int st = 4 >> gg;
        #pragma unroll
        for (int k0 = 0; k0 < PER; ++k0) {
            if (k0 & st) continue;              // static under full unroll
            const int k1 = k0 | st;
            const v2f p = amp[k0], q = amp[k1];
            v2f np = cmul(u00, p); cfma(np, u01, q);
            v2f nq = cmul(u10, p); cfma(nq, u11, q);
            amp[k0] = np;
            amp[k1] = nq;
        }
    }
}

__global__ __launch_bounds__(THREADS, 4)
void qcirc_kernel(const float* __restrict__ state,
                  const float* __restrict__ weights,
                  const float* __restrict__ head_w,
                  const float* __restrict__ head_b,
                  float* __restrict__ out)
{
    __shared__ __align__(16) v2f buf[2][PADC];
    __shared__ __align__(16) v2f Umat[NGATES][4];
    __shared__ float redbuf[THREADS / 64];

    const int t = threadIdx.x;                 // 9 bits
    const int b = blockIdx.x;

    // ---- 36 gate matrices. U = RZ(c)RY(b)RX(a); SU(2):
    // U = [[u00, -conj(u10)], [u10, conj(u00)]].
    if (t < NGATES) {
        const float* wp = weights + t * 3;
        float ha = 0.5f * wp[0], hb = 0.5f * wp[1], hc = 0.5f * wp[2];
        float ca = cosf(ha), sa = sinf(ha);
        float cb = cosf(hb), sb = sinf(hb);
        float ecr = cosf(hc), eci = -sinf(hc);   // e^{-i c/2}
        float t0 = cb * ca, t1 = sb * sa, t2 = sb * ca, t3 = cb * sa;
        float u00r =  ecr * t0 - eci * t1;
        float u00i =  ecr * t1 + eci * t0;
        float u10r =  ecr * t2 - eci * t3;
        float u10i = -ecr * t3 - eci * t2;
        Umat[t][0] = (v2f){ u00r,  u00i};   // u00
        Umat[t][1] = (v2f){-u10r,  u10i};   // u01 = -conj(u10)
        Umat[t][2] = (v2f){ u10r,  u10i};   // u10
        Umat[t][3] = (v2f){ u00r, -u00i};   // u11 = conj(u00)
    }

    // ---- Stage bases (f(i) = 18*(i>>4) + (i&15), v2f units).
    // P0: i=(k<<9)|t             f = 576k + bP0
    // P1: i=((t>>6)<<9)|(k<<6)|(t&63)  f = 72k + bP1
    // P2: i=((t>>3)<<6)|(k<<3)|(t&7)   f = {0,8,18,26,36,44,54,62}[k] + bP2
    // P3: i=(t<<3)|k             f = k + bP3   (b128 pairs, 16-B aligned)
    const int bP0 = 18 * (t >> 4) + (t & 15);
    const int bP1 = 576 * (t >> 6) + 18 * ((t >> 4) & 3) + (t & 15);
    const int bP2 = 72 * (t >> 3) + (t & 7);
    const int bP3 = 18 * (t >> 1) + 8 * (t & 1);

    // ---- Gather addresses (CNOT perm): amp[k] = old[j], j = gray12((k<<9)|t)
    //     = (K_k<<8) ^ gt,  K_k = (2k)^k,  gt = t^(t>>1)  (9-bit).
    // f(j) = 18*((K_k<<4) ^ (gt>>4)) + (gt&15).
    const int gt = t ^ (t >> 1);
    const int gl = gt & 15, gh = gt >> 4;
    int fg[PER];
    {
        const int KT[8] = {0, 3, 6, 5, 12, 15, 10, 9};
        #pragma unroll
        for (int k = 0; k < PER; ++k)
            fg[k] = 18 * ((KT[k] << 4) ^ gh) + gl;
    }

    // ---- Measurement constants. Final regs hold pre-perm state at
    // j=(t<<3)|k; logical m = invGray12(j): m[11:3]=invGray9(t),
    // m[2:0]=invGray3(k)^(parity(t)*7). Wire w <-> m bit (11-w).
    float hw[N_WIRES];
    #pragma unroll
    for (int w = 0; w < N_WIRES; ++w) hw[w] = head_w[w];
    int it = t ^ (t >> 1); it ^= it >> 2; it ^= it >> 4; it ^= it >> 8;  // invGray9
    float chi = 0.f;
    #pragma unroll
    for (int w = 0; w < 9; ++w)
        chi += ((it >> (8 - w)) & 1) ? -hw[w] : hw[w];
    const int parfill = (__popc(t) & 1) ? 7 : 0;

    // ---- Initial load, P0 layout: amp[k] = state[(k<<9)|t] (coalesced).
    v2f amp[PER];
    {
        const float* sp = state + (size_t)b * DIM;
        #pragma unroll
        for (int k = 0; k < PER; ++k)
            amp[k] = (v2f){sp[(k << 9) | t], 0.f};
    }
    __syncthreads();   // Umat ready

    #pragma unroll
    for (int l = 0; l < 3; ++l) {
        const int gb = l * 12;
        if (l > 0) {
            // Gather prev layer's P3 (buf1) through CNOT perm into P0 layout.
            // No anti-dep barrier needed: P0 writes target buf0.
            #pragma unroll
            for (int k = 0; k < PER; ++k) amp[k] = buf[1][fg[k]];
        }

        // P0: wires 0-2 (i bits 11-9 = k) -> write buf0
        apply3(amp, Umat, gb + 0);
        #pragma unroll
        for (int k = 0; k < PER; ++k) buf[0][bP0 + 576 * k] = amp[k];
        __syncthreads();

        // P1: wires 3-5 (i bits 8-6 = k): read buf0 -> write buf1
        #pragma unroll
        for (int k = 0; k < PER; ++k) amp[k] = buf[0][bP1 + 72 * k];
        apply3(amp, Umat, gb + 3);
        #pragma unroll
        for (int k = 0; k < PER; ++k) buf[1][bP1 + 72 * k] = amp[k];
        __syncthreads();

        // P2: wires 6-8 (i bits 5-3 = k): read buf1 -> write buf0
        #pragma unroll
        for (int k = 0; k < PER; ++k) {
            const int o2 = 18 * (k >> 1) + 8 * (k & 1);   // static
            amp[k] = buf[1][bP2 + o2];
        }
        apply3(amp, Umat, gb + 6);
        #pragma unroll
        for (int k = 0; k < PER; ++k) {
            const int o2 = 18 * (k >> 1) + 8 * (k & 1);
            buf[0][bP2 + o2] = amp[k];
        }
        __syncthreads();

        // P3: wires 9-11 (i bits 2-0 = k): read buf0 (b128) -> write buf1
        {
            const float4* r = reinterpret_cast<const float4*>(&buf[0][bP3]);
            #pragma unroll
            for (int j = 0; j < PER / 2; ++j) {
                float4 v = r[j];
                amp[2 * j]     = (v2f){v.x, v.y};
                amp[2 * j + 1] = (v2f){v.z, v.w};
            }
        }
        apply3(amp, Umat, gb + 9);
        if (l < 2) {
            float4* w = reinterpret_cast<float4*>(&buf[1][bP3]);
            #pragma unroll
            for (int j = 0; j < PER / 2; ++j)
                w[j] = make_float4(amp[2 * j].x, amp[2 * j].y,
                                   amp[2 * j + 1].x, amp[2 * j + 1].y);
            __syncthreads();
        }
    }

    // ---- Measurement.
    float acc = 0.f;
    #pragma unroll
    for (int k = 0; k < PER; ++k) {
        const int ml = (k ^ (k >> 1) ^ (k >> 2)) ^ parfill;  // m[2:0]
        float c = chi;
        c += ((ml >> 2) & 1) ? -hw[9]  : hw[9];
        c += ((ml >> 1) & 1) ? -hw[10] : hw[10];
        c += ( ml       & 1) ? -hw[11] : hw[11];
        float p = amp[k].x * amp[k].x + amp[k].y * amp[k].y;
        acc += p * c;
    }

    #pragma unroll
    for (int off = 32; off > 0; off >>= 1)
        acc += __shfl_down(acc, off, 64);
    if ((t & 63) == 0) redbuf[t >> 6] = acc;
    __syncthreads();
    if (t == 0) {
        float s = 0.f;
        #pragma unroll
        for (int q = 0; q < THREADS / 64; ++q) s += redbuf[q];
        out[b] = s + head_b[0];
    }
}

} // namespace

extern "C" void kernel_launch(void* const* d_in, const int* in_sizes, int n_in,
                              void* d_out, int out_size, void* d_ws, size_t ws_size,
                              hipStream_t stream)
{
    const float* state   = (const float*)d_in[0];  // (B, 4096) fp32
    const float* weights = (const float*)d_in[1];  // (3, 12, 3) fp32
    const float* head_w  = (const float*)d_in[2];  // (1, 12) fp32
    const float* head_b  = (const float*)d_in[3];  // (1,) fp32
    float* out = (float*)d_out;                    // (B,) fp32

    const int batch = in_sizes[0] / DIM;           // 512
    qcirc_kernel<<<batch, THREADS, 0, stream>>>(state, weights, head_w, head_b, out);
}